// Round 3
// baseline (127.128 us; speedup 1.0000x reference)
//
#include <hip/hip_runtime.h>
#include <math.h>

#define NB   16
#define NH   128
#define NW   128
#define NCLS 80
#define NPOS (NB * NH * NW)          // 262144 spatial positions
#define STRIDE_F 8.0f

#define BLOCKS_A (NPOS / 256)        // 1024: bbox decode, 1 thread/pos
#define BLOCKS_B (NPOS / 64)         // 4096: cls reduce, 4 lanes/pos, 64 pos/block

// Output layout (flat, reference return order):
//   [0 .. 4*NPOS)        xywh, float4 per position
//   [4*NPOS .. 5*NPOS)   argmax class index (as float)
//   [5*NPOS .. 6*NPOS)   conf = sqrt(sigmoid(center)*sigmoid(max_logit))
__global__ __launch_bounds__(256) void fcos_decode_kernel(
    const float* __restrict__ bbox,
    const float* __restrict__ center,
    const float* __restrict__ cls,
    float* __restrict__ out)
{
    const int bid = blockIdx.x;

    if (bid < BLOCKS_A) {
        // ---------- Role A: bbox ltrb->xywh, fully coalesced ----------
        const int pos = bid * 256 + threadIdx.x;
        const int w = pos & (NW - 1);
        const int h = (pos >> 7) & (NH - 1);

        const float4 ltrb = ((const float4*)bbox)[pos];
        const float l = expf(ltrb.x) * STRIDE_F;
        const float t = expf(ltrb.y) * STRIDE_F;
        const float r = expf(ltrb.z) * STRIDE_F;
        const float b = expf(ltrb.w) * STRIDE_F;

        const float cx = (float)w * STRIDE_F + STRIDE_F * 0.5f;
        const float cy = (float)h * STRIDE_F + STRIDE_F * 0.5f;

        ((float4*)out)[pos] = make_float4(cx - (l - r) * 0.5f,
                                          cy - (t - b) * 0.5f,
                                          l + r,
                                          t + b);
    } else {
        // ---------- Role B: class max/argmax + centerness conf ----------
        // 4 lanes per position, INTERLEAVED chunks: lane q owns float4 chunks
        // {q, q+4, q+8, q+12, q+16}. Per load instruction the 4 lanes of a
        // position cover one full 64B-aligned cache line (floats [16j,16j+16)).
        const int b    = bid - BLOCKS_A;
        const int wave = threadIdx.x >> 6;
        const int lane = threadIdx.x & 63;
        const int p    = lane >> 2;          // 0..15 position within wave
        const int q    = lane & 3;           // 0..3 interleave phase
        const int pos  = b * 64 + wave * 16 + p;

        const float4* cp4 = (const float4*)(cls + (size_t)pos * NCLS);
        const float4 v0 = cp4[q];
        const float4 v1 = cp4[q + 4];
        const float4 v2 = cp4[q + 8];
        const float4 v3 = cp4[q + 12];
        const float4 v4 = cp4[q + 16];

        // Within-lane scan in increasing class index (chunk bases 4q, 4(q+4), ...)
        float best = v0.x;
        int   idx  = 4 * q;
        #define SCAN4(v, cb)                                      \
            if ((v).x > best) { best = (v).x; idx = (cb);     }   \
            if ((v).y > best) { best = (v).y; idx = (cb) + 1; }   \
            if ((v).z > best) { best = (v).z; idx = (cb) + 2; }   \
            if ((v).w > best) { best = (v).w; idx = (cb) + 3; }
        if (v0.y > best) { best = v0.y; idx = 4 * q + 1; }
        if (v0.z > best) { best = v0.z; idx = 4 * q + 2; }
        if (v0.w > best) { best = v0.w; idx = 4 * q + 3; }
        SCAN4(v1, 4 * (q + 4))
        SCAN4(v2, 4 * (q + 8))
        SCAN4(v3, 4 * (q + 12))
        SCAN4(v4, 4 * (q + 16))
        #undef SCAN4

        // Butterfly over the 4-lane group; first-occurrence (smallest idx) tie-break.
        #pragma unroll
        for (int mask = 1; mask <= 2; mask <<= 1) {
            const float ov = __shfl_xor(best, mask);
            const int   oi = __shfl_xor(idx,  mask);
            if (ov > best || (ov == best && oi < idx)) { best = ov; idx = oi; }
        }

        if (q == 0) {
            // 16 active lanes, 64 contiguous bytes per wave per array — one line each.
            const float cen = center[pos];
            const float sc  = 1.0f / (1.0f + expf(-cen));
            const float ss  = 1.0f / (1.0f + expf(-best));
            out[(size_t)4 * NPOS + pos] = (float)idx;
            out[(size_t)5 * NPOS + pos] = sqrtf(sc * ss);
        }
    }
}

extern "C" void kernel_launch(void* const* d_in, const int* in_sizes, int n_in,
                              void* d_out, int out_size, void* d_ws, size_t ws_size,
                              hipStream_t stream)
{
    const float* bbox   = (const float*)d_in[0];
    const float* center = (const float*)d_in[1];
    const float* cls    = (const float*)d_in[2];
    float* out = (float*)d_out;

    fcos_decode_kernel<<<BLOCKS_A + BLOCKS_B, 256, 0, stream>>>(bbox, center, cls, out);
}